// Round 1
// baseline (298.425 us; speedup 1.0000x reference)
//
#include <hip/hip_runtime.h>
#include <hip/hip_bf16.h>

#define BB 32
#define TT 1024
#define JJ 64
#define DD 256

// ---------- wave helpers (wave64) ----------
__device__ __forceinline__ float wave_sum64(float v) {
    #pragma unroll
    for (int m = 32; m >= 1; m >>= 1) v += __shfl_xor(v, m, 64);
    return v;
}
__device__ __forceinline__ float wave_max64(float v) {
    #pragma unroll
    for (int m = 32; m >= 1; m >>= 1) v = fmaxf(v, __shfl_xor(v, m, 64));
    return v;
}

// ---------- K0: U' = U * w_hu (folded), uw[b,j] = U_j . w_u + b ----------
// grid: B*J/4 = 512 blocks, 256 threads (4 waves, one (b,j) row per wave)
__global__ __launch_bounds__(256) void k0_prep(const float* __restrict__ U,
                                               const float* __restrict__ w,
                                               const float* __restrict__ bp,
                                               float* __restrict__ Up,
                                               float* __restrict__ uw) {
    int wave = threadIdx.x >> 6;
    int lane = threadIdx.x & 63;
    int row  = blockIdx.x * 4 + wave;          // row in [0, B*J)
    const float* ur = U + (size_t)row * DD + lane * 4;
    float4 u   = *(const float4*)ur;
    float4 whu = *(const float4*)(w + 2 * DD + lane * 4);
    float4 wu  = *(const float4*)(w + DD + lane * 4);
    float4 o;
    o.x = u.x * whu.x; o.y = u.y * whu.y; o.z = u.z * whu.z; o.w = u.w * whu.w;
    *(float4*)(Up + (size_t)row * DD + lane * 4) = o;
    float p = fmaf(u.x, wu.x, fmaf(u.y, wu.y, fmaf(u.z, wu.z, u.w * wu.w)));
    p = wave_sum64(p);
    if (lane == 0) uw[row] = p + bp[0];
}

// ---------- K1: S + softmax_j + c2q + G[0:3D] ----------
// grid: B * (T/64) = 512 blocks, 256 threads. lane = j. LDS = 80KB -> 2 blocks/CU.
__global__ __launch_bounds__(256, 2) void k1_main(const float* __restrict__ H,
                                                  const float* __restrict__ U,
                                                  const float* __restrict__ Up,
                                                  const float* __restrict__ uw,
                                                  const float* __restrict__ w,
                                                  float* __restrict__ m_ws,
                                                  float* __restrict__ G,
                                                  float* __restrict__ c2q_out) {
    __shared__ float lds[20480];               // [0,16384): U tile (swizzled)  [16384,20480): A 64x64
    const int tid  = threadIdx.x;
    const int lane = tid & 63;                 // j
    const int wave = __builtin_amdgcn_readfirstlane(tid >> 6);
    const int b    = blockIdx.x >> 4;
    const int t0   = (blockIdx.x & 15) << 6;

    // ---- stage U' (w_hu-folded) into LDS, XOR-swizzled ----
    const float* Ub = Up + (size_t)b * JJ * DD;
    #pragma unroll
    for (int it = 0; it < 16; ++it) {
        int lin = it * 256 + tid;              // float4 index in [0, 4096)
        int j   = lin >> 6;
        int dcc = lin & 63;
        float4 v = *(const float4*)(Ub + (size_t)j * DD + dcc * 4);
        int byteoff = j * 1024 + ((dcc * 16) ^ ((j & 7) << 4));
        *(float4*)((char*)lds + byteoff) = v;
    }
    __syncthreads();

    const float uwj = uw[b * JJ + lane];       // includes +bias
    const float wh0 = w[lane], wh1 = w[64 + lane], wh2 = w[128 + lane], wh3 = w[192 + lane];
    const int   swz = (lane & 7) << 4;
    const char* urow = (const char*)lds + lane * 1024;
    const float* Hb  = H + (size_t)b * TT * DD;

    // ---- S loop: 4 row-groups of 4 rows per wave ----
    #pragma unroll 1
    for (int rg = 0; rg < 4; ++rg) {
        const int r0 = t0 + wave * 16 + rg * 4;
        const float* h0 = Hb + (size_t)(r0 + 0) * DD;
        const float* h1 = Hb + (size_t)(r0 + 1) * DD;
        const float* h2 = Hb + (size_t)(r0 + 2) * DD;
        const float* h3 = Hb + (size_t)(r0 + 3) * DD;
        float a0 = 0.f, a1 = 0.f, a2 = 0.f, a3 = 0.f;
        #pragma unroll 4
        for (int dc = 0; dc < 64; ++dc) {
            float4 u  = *(const float4*)(urow + ((dc * 16) ^ swz));
            float4 x0 = *(const float4*)(h0 + dc * 4);
            float4 x1 = *(const float4*)(h1 + dc * 4);
            float4 x2 = *(const float4*)(h2 + dc * 4);
            float4 x3 = *(const float4*)(h3 + dc * 4);
            a0 = fmaf(x0.x, u.x, fmaf(x0.y, u.y, fmaf(x0.z, u.z, fmaf(x0.w, u.w, a0))));
            a1 = fmaf(x1.x, u.x, fmaf(x1.y, u.y, fmaf(x1.z, u.z, fmaf(x1.w, u.w, a1))));
            a2 = fmaf(x2.x, u.x, fmaf(x2.y, u.y, fmaf(x2.z, u.z, fmaf(x2.w, u.w, a2))));
            a3 = fmaf(x3.x, u.x, fmaf(x3.y, u.y, fmaf(x3.z, u.z, fmaf(x3.w, u.w, a3))));
        }
        float sv[4] = {a0, a1, a2, a3};
        #pragma unroll
        for (int i = 0; i < 4; ++i) {
            const int row = r0 + i;
            const float* hr = Hb + (size_t)row * DD;
            // hw = H_row . w_h, lane-parallel then butterfly
            float hwp = fmaf(hr[lane], wh0,
                        fmaf(hr[64 + lane], wh1,
                        fmaf(hr[128 + lane], wh2, hr[192 + lane] * wh3)));
            float hw = wave_sum64(hwp);
            // softmax over j (invariant to +hw)
            float s  = sv[i] + uwj;
            float mx = wave_max64(s);
            float p  = __expf(s - mx);
            float l  = wave_sum64(p);
            lds[16384 + (wave * 16 + rg * 4 + i) * 64 + lane] = p * (1.0f / l);
            if (lane == 0) m_ws[b * TT + row] = mx + hw;   // full max_j S for b_att
        }
    }
    __syncthreads();

    // ---- restage RAW U into same LDS buffer (same swizzle) ----
    const float* Ug = U + (size_t)b * JJ * DD;
    #pragma unroll
    for (int it = 0; it < 16; ++it) {
        int lin = it * 256 + tid;
        int j   = lin >> 6;
        int dcc = lin & 63;
        float4 v = *(const float4*)(Ug + (size_t)j * DD + dcc * 4);
        int byteoff = j * 1024 + ((dcc * 16) ^ ((j & 7) << 4));
        *(float4*)((char*)lds + byteoff) = v;
    }
    __syncthreads();

    // ---- c2q = A @ U_raw, per wave: its own 16 rows; lane covers d = lane*4..+3
    float4 acc[16];
    #pragma unroll
    for (int r = 0; r < 16; ++r) { acc[r].x = 0.f; acc[r].y = 0.f; acc[r].z = 0.f; acc[r].w = 0.f; }
    const float* Arow = &lds[16384 + (wave * 16) * 64];
    #pragma unroll 4
    for (int j = 0; j < 64; ++j) {
        float4 u = *(const float4*)((const char*)lds + j * 1024 + ((lane * 16) ^ ((j & 7) << 4)));
        #pragma unroll
        for (int r = 0; r < 16; ++r) {
            float aj = Arow[r * 64 + j];
            acc[r].x = fmaf(aj, u.x, acc[r].x);
            acc[r].y = fmaf(aj, u.y, acc[r].y);
            acc[r].z = fmaf(aj, u.z, acc[r].z);
            acc[r].w = fmaf(aj, u.w, acc[r].w);
        }
    }

    // ---- write G[0:3D] + c2q ----
    const size_t Gbase = (size_t)b * TT * 1024;
    #pragma unroll 1
    for (int r = 0; r < 16; ++r) {
        const int row = t0 + wave * 16 + r;
        float4 h4 = *(const float4*)(Hb + (size_t)row * DD + lane * 4);
        float4 c  = acc[r];
        float4 hc;
        hc.x = h4.x * c.x; hc.y = h4.y * c.y; hc.z = h4.z * c.z; hc.w = h4.w * c.w;
        float* Grow = G + Gbase + (size_t)row * 1024;
        *(float4*)(Grow + lane * 4)        = h4;
        *(float4*)(Grow + 256 + lane * 4)  = c;
        *(float4*)(Grow + 512 + lane * 4)  = hc;
        *(float4*)(c2q_out + ((size_t)b * TT + row) * DD + lane * 4) = c;
    }
}

// ---------- K2: per-batch softmax over t of m; write wt; zero q2c ----------
// grid: 32 blocks, 256 threads
__global__ __launch_bounds__(256) void k2_batt(const float* __restrict__ m_ws,
                                               float* __restrict__ wt,
                                               float* __restrict__ q2c_out) {
    __shared__ float red[256];
    const int b = blockIdx.x, tid = threadIdx.x;
    float v0 = m_ws[b * TT + tid];
    float v1 = m_ws[b * TT + 256 + tid];
    float v2 = m_ws[b * TT + 512 + tid];
    float v3 = m_ws[b * TT + 768 + tid];
    red[tid] = fmaxf(fmaxf(v0, v1), fmaxf(v2, v3));
    __syncthreads();
    for (int s = 128; s >= 1; s >>= 1) {
        if (tid < s) red[tid] = fmaxf(red[tid], red[tid + s]);
        __syncthreads();
    }
    const float M = red[0];
    __syncthreads();
    float e0 = __expf(v0 - M), e1 = __expf(v1 - M), e2 = __expf(v2 - M), e3 = __expf(v3 - M);
    red[tid] = e0 + e1 + e2 + e3;
    __syncthreads();
    for (int s = 128; s >= 1; s >>= 1) {
        if (tid < s) red[tid] += red[tid + s];
        __syncthreads();
    }
    const float iz = 1.0f / red[0];
    wt[b * TT + tid]       = e0 * iz;
    wt[b * TT + 256 + tid] = e1 * iz;
    wt[b * TT + 512 + tid] = e2 * iz;
    wt[b * TT + 768 + tid] = e3 * iz;
    q2c_out[b * DD + tid] = 0.0f;              // zero for K2b atomics
}

// ---------- K2b: q2c[b,d] = sum_t wt[b,t] * H[b,t,d] (partial + atomic) ----------
// grid: B*8 = 256 blocks, 256 threads (thread = d)
__global__ __launch_bounds__(256) void k2b_q2c(const float* __restrict__ H,
                                               const float* __restrict__ wt,
                                               float* __restrict__ q2c_out) {
    const int b = blockIdx.x >> 3, c = blockIdx.x & 7, tid = threadIdx.x;
    const float* Hb = H + ((size_t)b * TT + c * 128) * DD;
    const float* wb = wt + b * TT + c * 128;
    float acc = 0.f;
    #pragma unroll 4
    for (int i = 0; i < 128; ++i) acc = fmaf(wb[i], Hb[(size_t)i * DD + tid], acc);
    atomicAdd(&q2c_out[b * DD + tid], acc);
}

// ---------- K3: G[:, :, 3D:4D] = H * q2c ----------
// grid: B*T*D/4/256 = 8192 blocks
__global__ __launch_bounds__(256) void k3_gtail(const float* __restrict__ H,
                                                const float* __restrict__ q2c,
                                                float* __restrict__ G) {
    const size_t idx = (size_t)blockIdx.x * 256 + threadIdx.x;  // float4 index
    const int d4 = (int)(idx & 63);
    const size_t bt = idx >> 6;
    const int b = (int)(bt >> 10);
    float4 h = *(const float4*)(H + idx * 4);
    float4 q = *(const float4*)(q2c + (size_t)b * DD + d4 * 4);
    float4 o;
    o.x = h.x * q.x; o.y = h.y * q.y; o.z = h.z * q.z; o.w = h.w * q.w;
    *(float4*)(G + bt * 1024 + 768 + d4 * 4) = o;
}

extern "C" void kernel_launch(void* const* d_in, const int* in_sizes, int n_in,
                              void* d_out, int out_size, void* d_ws, size_t ws_size,
                              hipStream_t stream) {
    const float* U  = (const float*)d_in[0];
    const float* H  = (const float*)d_in[1];
    const float* w  = (const float*)d_in[2];
    const float* bp = (const float*)d_in[3];
    float* out = (float*)d_out;

    // output layout: G (B,T,4D) | c2q (B,T,D) | q2c (B,1,D)
    float* G       = out;
    float* c2q_out = out + (size_t)BB * TT * 4 * DD;
    float* q2c_out = c2q_out + (size_t)BB * TT * DD;

    // workspace layout (floats): Up | uw | m | wt
    float* Up   = (float*)d_ws;
    float* uwp  = Up + (size_t)BB * JJ * DD;   // 524288
    float* m_ws = uwp + BB * JJ;               // +2048
    float* wtp  = m_ws + BB * TT;              // +32768

    k0_prep<<<BB * JJ / 4, 256, 0, stream>>>(U, w, bp, Up, uwp);
    k1_main<<<BB * (TT / 64), 256, 0, stream>>>(H, U, Up, uwp, w, m_ws, G, c2q_out);
    k2_batt<<<BB, 256, 0, stream>>>(m_ws, wtp, q2c_out);
    k2b_q2c<<<BB * 8, 256, 0, stream>>>(H, wtp, q2c_out);
    k3_gtail<<<BB * TT * DD / 4 / 256, 256, 0, stream>>>(H, q2c_out, G);
}

// Round 2
// 284.698 us; speedup vs baseline: 1.0482x; 1.0482x over previous
//
#include <hip/hip_runtime.h>
#include <hip/hip_bf16.h>

#define BB 32
#define TT 1024
#define JJ 64
#define DD 256

// ---------- K0: fused prep ----------
// blocks [0,512):   U' = U*w_hu, uw[b,j] = U_j.w_u + b   (wave per (b,j) row)
// blocks [512,1024): hw[b,t] = H_t.w_h                    (wave per 16 t-rows)
__global__ __launch_bounds__(256) void k0_prep(const float* __restrict__ U,
                                               const float* __restrict__ H,
                                               const float* __restrict__ w,
                                               const float* __restrict__ bp,
                                               float* __restrict__ Up,
                                               float* __restrict__ uw,
                                               float* __restrict__ hw) {
    const int wave = threadIdx.x >> 6;
    const int lane = threadIdx.x & 63;
    if (blockIdx.x < 512) {
        const int row = blockIdx.x * 4 + wave;     // (b,j) row in [0, B*J)
        float4 u   = *(const float4*)(U + (size_t)row * DD + lane * 4);
        float4 whu = *(const float4*)(w + 2 * DD + lane * 4);
        float4 wu  = *(const float4*)(w + DD + lane * 4);
        float4 o;
        o.x = u.x * whu.x; o.y = u.y * whu.y; o.z = u.z * whu.z; o.w = u.w * whu.w;
        *(float4*)(Up + (size_t)row * DD + lane * 4) = o;
        float p = fmaf(u.x, wu.x, fmaf(u.y, wu.y, fmaf(u.z, wu.z, u.w * wu.w)));
        #pragma unroll
        for (int m = 32; m >= 1; m >>= 1) p += __shfl_xor(p, m, 64);
        if (lane == 0) uw[row] = p + bp[0];
    } else {
        const int base = (blockIdx.x - 512) * 64 + wave * 16;   // t-row base in [0, B*T)
        float4 wh = *(const float4*)(w + lane * 4);
        float pr[16];
        #pragma unroll
        for (int r = 0; r < 16; ++r) {
            float4 h = *(const float4*)(H + (size_t)(base + r) * DD + lane * 4);
            pr[r] = fmaf(h.x, wh.x, fmaf(h.y, wh.y, fmaf(h.z, wh.z, h.w * wh.w)));
        }
        #pragma unroll
        for (int m = 32; m >= 1; m >>= 1) {
            #pragma unroll
            for (int r = 0; r < 16; ++r) pr[r] += __shfl_xor(pr[r], m, 64);
        }
        if (lane == 0) {
            #pragma unroll
            for (int r = 0; r < 16; ++r) hw[base + r] = pr[r];
        }
    }
}

// ---------- K1: S + softmax_j + c2q + G[0:3D] ----------
// grid: B*(T/64) = 512 blocks, 512 threads (8 waves, 8 t-rows each).
// LDS = 80KB -> 2 blocks/CU -> 16 waves/CU.
__global__ __launch_bounds__(512, 4) void k1_main(const float* __restrict__ H,
                                                  const float* __restrict__ U,
                                                  const float* __restrict__ Up,
                                                  const float* __restrict__ uw,
                                                  const float* __restrict__ hw,
                                                  float* __restrict__ m_ws,
                                                  float* __restrict__ G,
                                                  float* __restrict__ c2q_out) {
    __shared__ float lds[20480];               // [0,16384): U tile  [16384,20480): A 64x64
    const int tid  = threadIdx.x;
    const int lane = tid & 63;                 // j (S phase); d-quad (c2q phase)
    const int wave = __builtin_amdgcn_readfirstlane(tid >> 6);
    const int b    = blockIdx.x >> 4;
    const int t0   = (blockIdx.x & 15) << 6;
    const int r0   = t0 + wave * 8;

    // ---- stage U' (w_hu-folded): linear source, XOR-swizzled dest ----
    const float* Ub = Up + (size_t)b * JJ * DD;
    #pragma unroll
    for (int it = 0; it < 8; ++it) {
        const int j = it * 8 + wave;
        float4 v = *(const float4*)((const char*)Ub + j * 1024 + lane * 16);
        *(float4*)((char*)lds + j * 1024 + ((lane * 16) ^ ((j & 7) << 4))) = v;
    }
    __syncthreads();

    const float uwj = uw[b * JJ + lane];       // includes +bias
    const int   swz = (lane & 7) << 4;
    const char* urow = (const char*)lds + lane * 1024;
    const float* Hb  = H + (size_t)b * TT * DD;

    // ---- S dots: 8 rows per wave, all at once (uniform H loads) ----
    const float* h0 = Hb + (size_t)(r0 + 0) * DD;
    const float* h1 = Hb + (size_t)(r0 + 1) * DD;
    const float* h2 = Hb + (size_t)(r0 + 2) * DD;
    const float* h3 = Hb + (size_t)(r0 + 3) * DD;
    const float* h4p = Hb + (size_t)(r0 + 4) * DD;
    const float* h5 = Hb + (size_t)(r0 + 5) * DD;
    const float* h6 = Hb + (size_t)(r0 + 6) * DD;
    const float* h7 = Hb + (size_t)(r0 + 7) * DD;
    float a0 = 0.f, a1 = 0.f, a2 = 0.f, a3 = 0.f, a4 = 0.f, a5 = 0.f, a6 = 0.f, a7 = 0.f;
    #pragma unroll 2
    for (int dc = 0; dc < 64; ++dc) {
        float4 u  = *(const float4*)(urow + ((dc * 16) ^ swz));
        float4 x0 = *(const float4*)(h0 + dc * 4);
        float4 x1 = *(const float4*)(h1 + dc * 4);
        float4 x2 = *(const float4*)(h2 + dc * 4);
        float4 x3 = *(const float4*)(h3 + dc * 4);
        float4 x4 = *(const float4*)(h4p + dc * 4);
        float4 x5 = *(const float4*)(h5 + dc * 4);
        float4 x6 = *(const float4*)(h6 + dc * 4);
        float4 x7 = *(const float4*)(h7 + dc * 4);
        a0 = fmaf(x0.x, u.x, fmaf(x0.y, u.y, fmaf(x0.z, u.z, fmaf(x0.w, u.w, a0))));
        a1 = fmaf(x1.x, u.x, fmaf(x1.y, u.y, fmaf(x1.z, u.z, fmaf(x1.w, u.w, a1))));
        a2 = fmaf(x2.x, u.x, fmaf(x2.y, u.y, fmaf(x2.z, u.z, fmaf(x2.w, u.w, a2))));
        a3 = fmaf(x3.x, u.x, fmaf(x3.y, u.y, fmaf(x3.z, u.z, fmaf(x3.w, u.w, a3))));
        a4 = fmaf(x4.x, u.x, fmaf(x4.y, u.y, fmaf(x4.z, u.z, fmaf(x4.w, u.w, a4))));
        a5 = fmaf(x5.x, u.x, fmaf(x5.y, u.y, fmaf(x5.z, u.z, fmaf(x5.w, u.w, a5))));
        a6 = fmaf(x6.x, u.x, fmaf(x6.y, u.y, fmaf(x6.z, u.z, fmaf(x6.w, u.w, a6))));
        a7 = fmaf(x7.x, u.x, fmaf(x7.y, u.y, fmaf(x7.z, u.z, fmaf(x7.w, u.w, a7))));
    }
    __syncthreads();                           // all waves done reading U'

    // ---- issue raw-U restage loads (linear dest; c2q reads are contiguous) ----
    const float* Ug = U + (size_t)b * JJ * DD;
    float4 st[8];
    #pragma unroll
    for (int it = 0; it < 8; ++it) {
        const int j = it * 8 + wave;
        st[it] = *(const float4*)((const char*)Ug + j * 1024 + lane * 16);
    }

    // ---- softmax over j (8 interleaved wave reductions) — overlaps loads ----
    float s[8] = {a0 + uwj, a1 + uwj, a2 + uwj, a3 + uwj,
                  a4 + uwj, a5 + uwj, a6 + uwj, a7 + uwj};
    float mx[8];
    #pragma unroll
    for (int r = 0; r < 8; ++r) mx[r] = s[r];
    #pragma unroll
    for (int m = 32; m >= 1; m >>= 1) {
        #pragma unroll
        for (int r = 0; r < 8; ++r) mx[r] = fmaxf(mx[r], __shfl_xor(mx[r], m, 64));
    }
    float p[8], l[8];
    #pragma unroll
    for (int r = 0; r < 8; ++r) { p[r] = __expf(s[r] - mx[r]); l[r] = p[r]; }
    #pragma unroll
    for (int m = 32; m >= 1; m >>= 1) {
        #pragma unroll
        for (int r = 0; r < 8; ++r) l[r] += __shfl_xor(l[r], m, 64);
    }
    #pragma unroll
    for (int r = 0; r < 8; ++r)
        lds[16384 + (wave * 8 + r) * 64 + lane] = p[r] * (1.0f / l[r]);
    if (lane == 0) {
        #pragma unroll
        for (int r = 0; r < 8; ++r) m_ws[b * TT + r0 + r] = mx[r] + hw[b * TT + r0 + r];
    }

    // ---- write staged raw U (linear) ----
    #pragma unroll
    for (int it = 0; it < 8; ++it) {
        const int j = it * 8 + wave;
        *(float4*)((char*)lds + j * 1024 + lane * 16) = st[it];
    }
    __syncthreads();

    // ---- c2q = A @ U_raw: wave's 8 rows, lane covers d = lane*4..+3 ----
    float4 acc[8];
    #pragma unroll
    for (int r = 0; r < 8; ++r) { acc[r].x = 0.f; acc[r].y = 0.f; acc[r].z = 0.f; acc[r].w = 0.f; }
    const float* Arow = &lds[16384 + (wave * 8) * 64];
    #pragma unroll 2
    for (int j = 0; j < 64; ++j) {
        float4 u = *(const float4*)((const char*)lds + j * 1024 + lane * 16);
        #pragma unroll
        for (int r = 0; r < 8; ++r) {
            const float aj = Arow[r * 64 + j];   // broadcast read
            acc[r].x = fmaf(aj, u.x, acc[r].x);
            acc[r].y = fmaf(aj, u.y, acc[r].y);
            acc[r].z = fmaf(aj, u.z, acc[r].z);
            acc[r].w = fmaf(aj, u.w, acc[r].w);
        }
    }

    // ---- write G[0:3D] + c2q ----
    const size_t Gbase = (size_t)b * TT * 1024;
    #pragma unroll 1
    for (int r = 0; r < 8; ++r) {
        const int row = r0 + r;
        float4 h4 = *(const float4*)(Hb + (size_t)row * DD + lane * 4);
        float4 c  = acc[r];
        float4 hc;
        hc.x = h4.x * c.x; hc.y = h4.y * c.y; hc.z = h4.z * c.z; hc.w = h4.w * c.w;
        float* Grow = G + Gbase + (size_t)row * 1024;
        *(float4*)(Grow + lane * 4)        = h4;
        *(float4*)(Grow + 256 + lane * 4)  = c;
        *(float4*)(Grow + 512 + lane * 4)  = hc;
        *(float4*)(c2q_out + ((size_t)b * TT + row) * DD + lane * 4) = c;
    }
}

// ---------- K2: per-batch softmax over t of m; write wt; zero q2c ----------
__global__ __launch_bounds__(256) void k2_batt(const float* __restrict__ m_ws,
                                               float* __restrict__ wt,
                                               float* __restrict__ q2c_out) {
    __shared__ float red[256];
    const int b = blockIdx.x, tid = threadIdx.x;
    float v0 = m_ws[b * TT + tid];
    float v1 = m_ws[b * TT + 256 + tid];
    float v2 = m_ws[b * TT + 512 + tid];
    float v3 = m_ws[b * TT + 768 + tid];
    red[tid] = fmaxf(fmaxf(v0, v1), fmaxf(v2, v3));
    __syncthreads();
    for (int s = 128; s >= 1; s >>= 1) {
        if (tid < s) red[tid] = fmaxf(red[tid], red[tid + s]);
        __syncthreads();
    }
    const float M = red[0];
    __syncthreads();
    float e0 = __expf(v0 - M), e1 = __expf(v1 - M), e2 = __expf(v2 - M), e3 = __expf(v3 - M);
    red[tid] = e0 + e1 + e2 + e3;
    __syncthreads();
    for (int s = 128; s >= 1; s >>= 1) {
        if (tid < s) red[tid] += red[tid + s];
        __syncthreads();
    }
    const float iz = 1.0f / red[0];
    wt[b * TT + tid]       = e0 * iz;
    wt[b * TT + 256 + tid] = e1 * iz;
    wt[b * TT + 512 + tid] = e2 * iz;
    wt[b * TT + 768 + tid] = e3 * iz;
    q2c_out[b * DD + tid] = 0.0f;              // zero for K2b atomics
}

// ---------- K2b: q2c[b,d] partial sums + atomicAdd; 512 blocks ----------
__global__ __launch_bounds__(256) void k2b_q2c(const float* __restrict__ H,
                                               const float* __restrict__ wt,
                                               float* __restrict__ q2c_out) {
    const int b = blockIdx.x >> 4, c = blockIdx.x & 15, tid = threadIdx.x;
    const float* Hb = H + ((size_t)b * TT + c * 64) * DD;
    const float* wb = wt + b * TT + c * 64;
    float acc = 0.f;
    #pragma unroll 4
    for (int i = 0; i < 64; ++i) acc = fmaf(wb[i], Hb[(size_t)i * DD + tid], acc);
    atomicAdd(&q2c_out[b * DD + tid], acc);
}

// ---------- K3: G[:, :, 3D:4D] = H * q2c ----------
__global__ __launch_bounds__(256) void k3_gtail(const float* __restrict__ H,
                                                const float* __restrict__ q2c,
                                                float* __restrict__ G) {
    const size_t idx = (size_t)blockIdx.x * 256 + threadIdx.x;  // float4 index
    const int d4 = (int)(idx & 63);
    const size_t bt = idx >> 6;
    const int b = (int)(bt >> 10);
    float4 h = *(const float4*)(H + idx * 4);
    float4 q = *(const float4*)(q2c + (size_t)b * DD + d4 * 4);
    float4 o;
    o.x = h.x * q.x; o.y = h.y * q.y; o.z = h.z * q.z; o.w = h.w * q.w;
    *(float4*)(G + bt * 1024 + 768 + d4 * 4) = o;
}

extern "C" void kernel_launch(void* const* d_in, const int* in_sizes, int n_in,
                              void* d_out, int out_size, void* d_ws, size_t ws_size,
                              hipStream_t stream) {
    const float* U  = (const float*)d_in[0];
    const float* H  = (const float*)d_in[1];
    const float* w  = (const float*)d_in[2];
    const float* bp = (const float*)d_in[3];
    float* out = (float*)d_out;

    // output layout: G (B,T,4D) | c2q (B,T,D) | q2c (B,1,D)
    float* G       = out;
    float* c2q_out = out + (size_t)BB * TT * 4 * DD;
    float* q2c_out = c2q_out + (size_t)BB * TT * DD;

    // workspace (floats): Up | uw | m | wt | hw
    float* Up   = (float*)d_ws;
    float* uwp  = Up + (size_t)BB * JJ * DD;   // 524288
    float* m_ws = uwp + BB * JJ;               // +2048
    float* wtp  = m_ws + BB * TT;              // +32768
    float* hwp  = wtp + BB * TT;               // +32768

    k0_prep<<<1024, 256, 0, stream>>>(U, H, w, bp, Up, uwp, hwp);
    k1_main<<<BB * (TT / 64), 512, 0, stream>>>(H, U, Up, uwp, hwp, m_ws, G, c2q_out);
    k2_batt<<<BB, 256, 0, stream>>>(m_ws, wtp, q2c_out);
    k2b_q2c<<<BB * 16, 256, 0, stream>>>(H, wtp, q2c_out);
    k3_gtail<<<BB * TT * DD / 4 / 256, 256, 0, stream>>>(H, q2c_out, G);
}